// Round 1
// baseline (40.522 us; speedup 1.0000x reference)
//
#include <hip/hip_runtime.h>
#include <math.h>

// ROI crop-resize (ROI-align style, aligned sampling) over NHWC f32 feature map.
// One wave (64 lanes) per output sample point (n,i,j); each lane handles 4
// channels via float4 (C=256 = 64 lanes * 4). All per-point scalars are
// wave-uniform; loads/stores are contiguous 1KB per pixel row -> coalesced.
__global__ __launch_bounds__(256) void roi_align_kernel(
    const float* __restrict__ fm,      // [H, W, C]
    const float* __restrict__ props,   // [nprop, 4] (x1,y1,x2,y2)
    float* __restrict__ out,           // [nprop, S, S, C]
    int S, int nprop, int H, int W, int C)
{
    const int wave = (int)((blockIdx.x * blockDim.x + threadIdx.x) >> 6);
    const int lane = threadIdx.x & 63;
    const int total = nprop * S * S;
    if (wave >= total) return;

    const int n  = wave / (S * S);
    const int ij = wave - n * (S * S);
    const int i  = ij / S;         // y sample index
    const int j  = ij - i * S;     // x sample index

    // Proposal box, rounded half-to-even like jnp.round (rintf w/ default RNE).
    const float4 p = ((const float4*)props)[n];
    const float x1 = fmaxf(rintf(p.x), 0.0f);
    const float y1 = fmaxf(rintf(p.y), 0.0f);
    const float x2 = fminf(rintf(p.z), (float)(W - 1));
    const float y2 = fminf(rintf(p.w), (float)(H - 1));
    const float h  = y2 - y1;
    const float w  = x2 - x1;

    const float ty = ((float)i + 0.5f) / (float)S;
    const float tx = ((float)j + 0.5f) / (float)S;
    const float sy = fminf(fmaxf(ty * h - 0.5f, 0.0f), fmaxf(h - 1.0f, 0.0f)) + y1;
    const float sx = fminf(fmaxf(tx * w - 0.5f, 0.0f), fmaxf(w - 1.0f, 0.0f)) + x1;

    const float y0f = floorf(sy);
    const float x0f = floorf(sx);
    const int y0i = (int)y0f;
    const int x0i = (int)x0f;
    const int y1i = min(y0i + 1, H - 1);
    const int x1i = min(x0i + 1, W - 1);
    const float wy = sy - y0f;
    const float wx = sx - x0f;
    const float owy = 1.0f - wy;
    const float owx = 1.0f - wx;

    const float4* r00 = (const float4*)(fm + ((size_t)y0i * W + x0i) * C);
    const float4* r01 = (const float4*)(fm + ((size_t)y0i * W + x1i) * C);
    const float4* r10 = (const float4*)(fm + ((size_t)y1i * W + x0i) * C);
    const float4* r11 = (const float4*)(fm + ((size_t)y1i * W + x1i) * C);
    float4* o = (float4*)(out + (size_t)wave * C);

    // C/4 float4's per pixel row; C=256 -> exactly 64, one per lane.
    const int nvec = C >> 2;
    for (int v = lane; v < nvec; v += 64) {
        const float4 v00 = r00[v];
        const float4 v01 = r01[v];
        const float4 v10 = r10[v];
        const float4 v11 = r11[v];
        float4 r;
        r.x = (v00.x * owx + v01.x * wx) * owy + (v10.x * owx + v11.x * wx) * wy;
        r.y = (v00.y * owx + v01.y * wx) * owy + (v10.y * owx + v11.y * wx) * wy;
        r.z = (v00.z * owx + v01.z * wx) * owy + (v10.z * owx + v11.z * wx) * wy;
        r.w = (v00.w * owx + v01.w * wx) * owy + (v10.w * owx + v11.w * wx) * wy;
        o[v] = r;
    }
}

extern "C" void kernel_launch(void* const* d_in, const int* in_sizes, int n_in,
                              void* d_out, int out_size, void* d_ws, size_t ws_size,
                              hipStream_t stream)
{
    const float* fm    = (const float*)d_in[0];   // (1, 256, 256, 256) f32
    const float* props = (const float*)d_in[1];   // (1024, 4) f32
    float* out = (float*)d_out;

    const int H = 256, W = 256, C = 256;          // fixed by setup_inputs
    const int nprop = in_sizes[1] / 4;
    // out_size = nprop * S * S * C
    int S = 1;
    {
        const long long per = (long long)nprop * C;
        const long long ss = (long long)out_size / per;
        // integer sqrt of ss
        while ((long long)(S + 1) * (S + 1) <= ss) ++S;
    }

    const int total_waves = nprop * S * S;        // one wave per sample point
    const int waves_per_block = 4;                // 256 threads
    const int blocks = (total_waves + waves_per_block - 1) / waves_per_block;
    roi_align_kernel<<<blocks, 256, 0, stream>>>(fm, props, out, S, nprop, H, W, C);
}